// Round 6
// baseline (86.794 us; speedup 1.0000x reference)
//
#include <hip/hip_runtime.h>
#include <math.h>

// Two states per wave; 256 amps/state = 64 lanes x 4 slots (amp = lane*4+slot).
// State A in .x, B in .y of float2 regs (packed v_pk_* math).
// Round-6: kernel is bpermute-throughput-bound (R2-R5: time tracks bperm count
// at ~8cyc/op on the per-CU LDS pipe). Changes:
//  (1) xor16/32 exchanges -> v_permlane{16,32}_swap_b32 on the VALU pipe.
//      swap(v,v) returns {own,foreign} unordered per lane; r0^r1^own = foreign
//      (bitwise-exact, semantics-order-proof). 0 LDS ops.
//  (2) composed-CNOT ring: source-side merge. Gray map is bijective and the
//      reading dest's parity == popcount(src_lane)&1, so z = psel ? vHI : vLO
//      lets ONE bpermute serve both parities -> 8 bperm/ring (was 16), no
//      dest-side select.
// LDS-pipe load: 4 rings x 8 = 32 bperm/wave (was 160).
// Qubit q <-> amp bit (7-q); amp bits 7..2 = lane bits 5..0, bits 1..0 = slot.

typedef float f2 __attribute__((ext_vector_type(2)));

#define RLF(v, i) __int_as_float(__builtin_amdgcn_readlane(__float_as_int(v), (i)))
#define BPF(a, v) __int_as_float(__builtin_amdgcn_ds_bpermute((a), __float_as_int(v)))
#define DPPF(v, ctrl) __uint_as_float((unsigned)__builtin_amdgcn_update_dpp( \
    0, (int)__float_as_uint(v), (ctrl), 0xf, 0xf, true))

__device__ __forceinline__ f2 mk2(float a, float b) { f2 r; r.x = a; r.y = b; return r; }

#define PX1S(v)  DPPF((v), 0xB1)
#define PX2S(v)  DPPF((v), 0x4E)
#define PX4S(v)  DPPF(DPPF((v), 0x141), 0x1B)
#define PX8S(v)  DPPF((v), 0x128)

#if __has_builtin(__builtin_amdgcn_permlane16_swap)
__device__ __forceinline__ float px16s(float v, int a16) {
    const unsigned uv = __float_as_uint(v);
    auto r = __builtin_amdgcn_permlane16_swap(uv, uv, false, false);
    return __uint_as_float(r[0] ^ r[1] ^ uv);
}
#else
__device__ __forceinline__ float px16s(float v, int a16) { return BPF(a16, v); }
#endif

#if __has_builtin(__builtin_amdgcn_permlane32_swap)
__device__ __forceinline__ float px32s(float v, int a32) {
    const unsigned uv = __float_as_uint(v);
    auto r = __builtin_amdgcn_permlane32_swap(uv, uv, false, false);
    return __uint_as_float(r[0] ^ r[1] ^ uv);
}
#else
__device__ __forceinline__ float px32s(float v, int a32) { return BPF(a32, v); }
#endif

#define PX1(v)  mk2(PX1S((v).x), PX1S((v).y))
#define PX2(v)  mk2(PX2S((v).x), PX2S((v).y))
#define PX4(v)  mk2(PX4S((v).x), PX4S((v).y))
#define PX8(v)  mk2(PX8S((v).x), PX8S((v).y))
#define PX16(v) mk2(px16s((v).x, a16), px16s((v).y, a16))
#define PX32(v) mk2(px32s((v).x, a32), px32s((v).y, a32))
#define FMA2(a, b, c) __builtin_elementwise_fma((a), (b), (c))

__global__ __launch_bounds__(256, 8) void vqcnn_wave(
    const float* __restrict__ x,          // (B, 4, 8)
    const float* __restrict__ crx_theta,  // (10,)
    const float* __restrict__ w1,         // (10, 2)
    const float* __restrict__ b1,         // (10,)
    const float* __restrict__ w2,         // (1, 10)
    const float* __restrict__ b2,         // (1,)
    float* __restrict__ out)              // (B, 1)
{
    const int lane = threadIdx.x & 63;
    const int bA   = blockIdx.x * 8 + (threadIdx.x >> 6) * 2;
    const int bB   = bA + 1;

    // per-wave angle tables: lanes 0..31 RY (per state), lanes 32..41 CRX (shared)
    float cvA, svA, cvB, svB;
    {
        float angA = 0.0f, angB = 0.0f;
        if (lane < 32) {
            angA = x[bA * 32 + lane];
            angB = x[bB * 32 + lane];
        } else if (lane < 42) {
            angA = angB = crx_theta[lane - 32];
        }
        __sincosf(0.5f * angA, &svA, &cvA);
        __sincosf(0.5f * angB, &svB, &cvB);
    }

    // bpermute byte addresses (ring + fallback paths)
    const int a16 = (lane ^ 16) << 2;
    const int a32 = (lane ^ 32) << 2;
    const int g4  = (lane ^ (lane >> 1)) << 2;  // gray(lane)*4 : ring src lane
    const int g4b = g4 ^ (48 << 2);
    const bool psel = (__builtin_popcount(lane) & 1) != 0;  // parity(src lane)

#define RL2C(i) mk2(RLF(cvA, (i)), RLF(cvB, (i)))
#define RL2S(i) mk2(RLF(svA, (i)), RLF(svB, (i)))

    // ---- cycle 0: product state |0> -> prod_q RY(q) ----
    f2 vv0, vv1, vv2, vv3;
    {
#define SEL0(bit, i) ((lane & (bit)) ? RL2S(i) : RL2C(i))
        f2 L = SEL0(32, 0) * SEL0(16, 1);
        L = L * SEL0(8, 2);
        L = L * SEL0(4, 3);
        L = L * SEL0(2, 4);
        L = L * SEL0(1, 5);
        const f2 c6 = RL2C(6), s6 = RL2S(6);
        const f2 c7 = RL2C(7), s7 = RL2S(7);
        const f2 Lc6 = L * c6, Ls6 = L * s6;
        vv0 = Lc6 * c7; vv1 = Lc6 * s7; vv2 = Ls6 * c7; vv3 = Ls6 * s7;
    }

    // ring: v0 <- z0[gray], v1 <- z1[gray^48], v2 <- z2[gray], v3 <- z3[gray^48]
    // with source-side parity select (one bperm serves both dest parities).
#define RING() {                                                             \
    const f2 z0 = psel ? vv2 : vv0;                                          \
    const f2 z1 = psel ? vv3 : vv1;                                          \
    const f2 z2 = psel ? vv1 : vv3;                                          \
    const f2 z3 = psel ? vv0 : vv2;                                          \
    vv0 = mk2(BPF(g4,  z0.x), BPF(g4,  z0.y));                               \
    vv1 = mk2(BPF(g4b, z1.x), BPF(g4b, z1.y));                               \
    vv2 = mk2(BPF(g4,  z2.x), BPF(g4,  z2.y));                               \
    vv3 = mk2(BPF(g4b, z3.x), BPF(g4b, z3.y)); }
    RING()

#define RY_G(ia, mask, PART) {                                               \
    const f2 c = RL2C(ia), s = RL2S(ia);                                     \
    const f2 ss = (lane & (mask)) ? s : -s;                                  \
    const f2 p0 = PART(vv0), p1 = PART(vv1);                                 \
    const f2 p2 = PART(vv2), p3 = PART(vv3);                                 \
    vv0 = FMA2(ss, p0, c * vv0); vv1 = FMA2(ss, p1, c * vv1);                \
    vv2 = FMA2(ss, p2, c * vv2); vv3 = FMA2(ss, p3, c * vv3); }

#define RY_SLOT1(ia) {                                                       \
    const f2 c = RL2C(ia), s = RL2S(ia);                                     \
    const f2 n0 = c*vv0 - s*vv2, n2 = FMA2(s, vv0, c*vv2);                   \
    const f2 n1 = c*vv1 - s*vv3, n3 = FMA2(s, vv1, c*vv3);                   \
    vv0 = n0; vv1 = n1; vv2 = n2; vv3 = n3; }

#define RY_SLOT0(ia) {                                                       \
    const f2 c = RL2C(ia), s = RL2S(ia);                                     \
    const f2 n0 = c*vv0 - s*vv1, n1 = FMA2(s, vv0, c*vv1);                   \
    const f2 n2 = c*vv2 - s*vv3, n3 = FMA2(s, vv2, c*vv3);                   \
    vv0 = n0; vv1 = n1; vv2 = n2; vv3 = n3; }

    // ---- cycles 1..3: 8 RY + composed CNOT ring, real arithmetic ----
    #pragma unroll
    for (int cyc = 1; cyc < 4; ++cyc) {
        const int base = cyc * 8;
        RY_G(base + 0, 32, PX32)
        RY_G(base + 1, 16, PX16)
        RY_G(base + 2,  8, PX8)
        RY_G(base + 3,  4, PX4)
        RY_G(base + 4,  2, PX2)
        RY_G(base + 5,  1, PX1)
        RY_SLOT1(base + 6)
        RY_SLOT0(base + 7)
        RING()
    }

    // ---- Phase 2: 10 CRX gates (complex from here) ----
    f2 rr0 = vv0, rr1 = vv1, rr2 = vv2, rr3 = vv3;
    f2 ii0 = {0.f, 0.f}, ii1 = {0.f, 0.f}, ii2 = {0.f, 0.f}, ii3 = {0.f, 0.f};

#define CRX_G(gi, cmask, PART) {                                             \
    const f2 c = RL2C(32 + (gi)), s = RL2S(32 + (gi));                       \
    const bool ct = (lane & (cmask)) != 0;                                   \
    f2 pr, pi, nr, ni;                                                       \
    pr = PART(rr0); pi = PART(ii0);                                          \
    nr = FMA2(s, pi, c*rr0); ni = c*ii0 - s*pr;                              \
    rr0 = ct?nr:rr0; ii0 = ct?ni:ii0;                                        \
    pr = PART(rr1); pi = PART(ii1);                                          \
    nr = FMA2(s, pi, c*rr1); ni = c*ii1 - s*pr;                              \
    rr1 = ct?nr:rr1; ii1 = ct?ni:ii1;                                        \
    pr = PART(rr2); pi = PART(ii2);                                          \
    nr = FMA2(s, pi, c*rr2); ni = c*ii2 - s*pr;                              \
    rr2 = ct?nr:rr2; ii2 = ct?ni:ii2;                                        \
    pr = PART(rr3); pi = PART(ii3);                                          \
    nr = FMA2(s, pi, c*rr3); ni = c*ii3 - s*pr;                              \
    rr3 = ct?nr:rr3; ii3 = ct?ni:ii3; }

    CRX_G(0, 32, PX16)   // ctrl lane^32, target lane^16
    CRX_G(1, 16, PX8)
    CRX_G(2,  8, PX4)
    CRX_G(3,  4, PX2)
    CRX_G(4,  2, PX1)
    {   // gate 5: ctrl lane bit0, target amp bit1 (slot pairs (0,2),(1,3))
        const bool l0 = (lane & 1) != 0;
        const f2 c = RL2C(37), s = RL2S(37);
        const f2 nr0 = FMA2(s, ii2, c*rr0), ni0 = c*ii0 - s*rr2;
        const f2 nr2 = FMA2(s, ii0, c*rr2), ni2 = c*ii2 - s*rr0;
        const f2 nr1 = FMA2(s, ii3, c*rr1), ni1 = c*ii1 - s*rr3;
        const f2 nr3 = FMA2(s, ii1, c*rr3), ni3 = c*ii3 - s*rr1;
        rr0 = l0?nr0:rr0; ii0 = l0?ni0:ii0; rr1 = l0?nr1:rr1; ii1 = l0?ni1:ii1;
        rr2 = l0?nr2:rr2; ii2 = l0?ni2:ii2; rr3 = l0?nr3:rr3; ii3 = l0?ni3:ii3;
    }
    {   // gate 6: ctrl slot bit1 (slots 2,3), target amp bit0 (pair (2,3))
        const f2 c = RL2C(38), s = RL2S(38);
        const f2 nr2 = FMA2(s, ii3, c*rr2), ni2 = c*ii2 - s*rr3;
        const f2 nr3 = FMA2(s, ii2, c*rr3), ni3 = c*ii3 - s*rr2;
        rr2 = nr2; ii2 = ni2; rr3 = nr3; ii3 = ni3;
    }
    {   // gate 7: ctrl slot bit0 (slots 1,3), target amp bit7 (lane^32)
        const f2 c = RL2C(39), s = RL2S(39);
        const f2 pr1 = PX32(rr1), pi1 = PX32(ii1);
        const f2 pr3 = PX32(rr3), pi3 = PX32(ii3);
        const f2 nr1 = FMA2(s, pi1, c*rr1), ni1 = c*ii1 - s*pr1;
        const f2 nr3 = FMA2(s, pi3, c*rr3), ni3 = c*ii3 - s*pr3;
        rr1 = nr1; ii1 = ni1; rr3 = nr3; ii3 = ni3;
    }
    CRX_G(8, 32, PX16)
    CRX_G(9, 16, PX8)

    // ---- probabilities, <Z_3> (amp bit4 -> lane bit2), <Z_7> (amp bit0 -> slot0) ----
    const f2 p0 = FMA2(rr0, rr0, ii0*ii0), p1 = FMA2(rr1, rr1, ii1*ii1);
    const f2 p2 = FMA2(rr2, rr2, ii2*ii2), p3 = FMA2(rr3, rr3, ii3*ii3);
    const f2 sum = (p0 + p1) + (p2 + p3);
    f2 vq7 = (p0 + p2) - (p1 + p3);
    f2 vq3 = (lane & 4) ? -sum : sum;
    vq3 = vq3 + PX1(vq3);   vq7 = vq7 + PX1(vq7);
    vq3 = vq3 + PX2(vq3);   vq7 = vq7 + PX2(vq7);
    vq3 = vq3 + PX4(vq3);   vq7 = vq7 + PX4(vq7);
    vq3 = vq3 + PX8(vq3);   vq7 = vq7 + PX8(vq7);
    vq3 = vq3 + PX16(vq3);  vq7 = vq7 + PX16(vq7);
    vq3 = vq3 + PX32(vq3);  vq7 = vq7 + PX32(vq7);

    // ---- MLP: lane u (<10) computes hidden unit u for both states ----
    float wa = 0.f, wb = 0.f, bb = 0.f, wc = 0.f;
    if (lane < 10) {
        wa = w1[2 * lane];
        wb = w1[2 * lane + 1];
        bb = b1[lane];
        wc = w2[lane];
    }
    const f2 z = FMA2(mk2(wa, wa), vq3, FMA2(mk2(wb, wb), vq7, mk2(bb, bb)));
    const f2 e = mk2(__expf(2.0f * z.x), __expf(2.0f * z.y));
    const f2 h = mk2(1.0f - 2.0f * __builtin_amdgcn_rcpf(e.x + 1.0f),
                     1.0f - 2.0f * __builtin_amdgcn_rcpf(e.y + 1.0f));  // tanh
    f2 acc = mk2(wc, wc) * h;               // lanes >=10 contribute 0
    acc = acc + PX1(acc);
    acc = acc + PX2(acc);
    acc = acc + PX4(acc);
    acc = acc + PX8(acc);                   // sum over lanes 0..15 (row-local)
    if (lane == 0) {
        const float bias = b2[0];
        out[bA] = __builtin_amdgcn_rcpf(1.0f + __expf(-(acc.x + bias)));
        out[bB] = __builtin_amdgcn_rcpf(1.0f + __expf(-(acc.y + bias)));
    }
}

extern "C" void kernel_launch(void* const* d_in, const int* in_sizes, int n_in,
                              void* d_out, int out_size, void* d_ws, size_t ws_size,
                              hipStream_t stream) {
    const float* x         = (const float*)d_in[0];
    const float* crx_theta = (const float*)d_in[1];
    const float* w1        = (const float*)d_in[2];
    const float* b1        = (const float*)d_in[3];
    const float* w2        = (const float*)d_in[4];
    const float* b2        = (const float*)d_in[5];
    float* out = (float*)d_out;

    const int B = in_sizes[0] / 32;  // x is (B, 4, 8)
    vqcnn_wave<<<B / 8, 256, 0, stream>>>(x, crx_theta, w1, b1, w2, b2, out);
}

// Round 7
// 82.499 us; speedup vs baseline: 1.0521x; 1.0521x over previous
//
#include <hip/hip_runtime.h>
#include <math.h>

// Four states per wave as TWO independent packed-f2 chains (U: states A,B;
// W: states C,D), interleaved at macro level. R4-R6 evidence: time tracks
// dependency-chain length, not issue count (packed R5 ~= scalar R4; R6's
// +2-op-per-exchange chain regressed). => latency-bound. Two independent
// chains/wave double the scheduler's bubble-filling material.
// Cross-lane: xor1/2/4/8 via DPP (VALU), xor16/32 via ds_bpermute (reverted
// from R6's permlane swaps, which regressed). Ring: R6's source-side parity
// merge (8 bperm/ring/stream, proven correct).
// Qubit q <-> amp bit (7-q); amp bits 7..2 = lane bits 5..0, bits 1..0 = slot.

typedef float f2 __attribute__((ext_vector_type(2)));

#define RLF(v, i) __int_as_float(__builtin_amdgcn_readlane(__float_as_int(v), (i)))
#define BPF(a, v) __int_as_float(__builtin_amdgcn_ds_bpermute((a), __float_as_int(v)))
#define DPPF(v, ctrl) __uint_as_float((unsigned)__builtin_amdgcn_update_dpp( \
    0, (int)__float_as_uint(v), (ctrl), 0xf, 0xf, true))

__device__ __forceinline__ f2 mk2(float a, float b) { f2 r; r.x = a; r.y = b; return r; }

#define PX1S(v)  DPPF((v), 0xB1)
#define PX2S(v)  DPPF((v), 0x4E)
#define PX4S(v)  DPPF(DPPF((v), 0x141), 0x1B)
#define PX8S(v)  DPPF((v), 0x128)

#define PX1(v)  mk2(PX1S((v).x), PX1S((v).y))
#define PX2(v)  mk2(PX2S((v).x), PX2S((v).y))
#define PX4(v)  mk2(PX4S((v).x), PX4S((v).y))
#define PX8(v)  mk2(PX8S((v).x), PX8S((v).y))
#define PX16(v) mk2(BPF(a16, (v).x), BPF(a16, (v).y))
#define PX32(v) mk2(BPF(a32, (v).x), BPF(a32, (v).y))
#define FMA2(a, b, c) __builtin_elementwise_fma((a), (b), (c))

__global__ __launch_bounds__(256, 4) void vqcnn_wave(
    const float* __restrict__ x,          // (B, 4, 8)
    const float* __restrict__ crx_theta,  // (10,)
    const float* __restrict__ w1,         // (10, 2)
    const float* __restrict__ b1,         // (10,)
    const float* __restrict__ w2,         // (1, 10)
    const float* __restrict__ b2,         // (1,)
    float* __restrict__ out)              // (B, 1)
{
    const int lane = threadIdx.x & 63;
    const int bA   = blockIdx.x * 16 + (threadIdx.x >> 6) * 4;  // A,B,C,D = bA..bA+3

    // angle tables: lanes 0..31 RY per state, lanes 32..41 CRX (shared)
    float cvA, svA, cvB, svB, cvC, svC, cvD, svD;
    {
        float aA = 0.f, aB = 0.f, aC = 0.f, aD = 0.f;
        if (lane < 32) {
            aA = x[(bA + 0) * 32 + lane];
            aB = x[(bA + 1) * 32 + lane];
            aC = x[(bA + 2) * 32 + lane];
            aD = x[(bA + 3) * 32 + lane];
        } else if (lane < 42) {
            aA = aB = aC = aD = crx_theta[lane - 32];
        }
        __sincosf(0.5f * aA, &svA, &cvA);
        __sincosf(0.5f * aB, &svB, &cvB);
        __sincosf(0.5f * aC, &svC, &cvC);
        __sincosf(0.5f * aD, &svD, &cvD);
    }

    const int a16 = (lane ^ 16) << 2;
    const int a32 = (lane ^ 32) << 2;
    const int g4  = (lane ^ (lane >> 1)) << 2;  // gray(lane)*4 : ring src lane
    const int g4b = g4 ^ (48 << 2);
    const bool psel = (__builtin_popcount(lane) & 1) != 0;

#define RLCu(i) mk2(RLF(cvA, (i)), RLF(cvB, (i)))
#define RLSu(i) mk2(RLF(svA, (i)), RLF(svB, (i)))
#define RLCw(i) mk2(RLF(cvC, (i)), RLF(cvD, (i)))
#define RLSw(i) mk2(RLF(svC, (i)), RLF(svD, (i)))

    // ---- cycle 0: product state |0> -> prod_q RY(q), both streams ----
    f2 vv0u, vv1u, vv2u, vv3u, vv0w, vv1w, vv2w, vv3w;
    {
#define SELu(bit, i) ((lane & (bit)) ? RLSu(i) : RLCu(i))
#define SELw(bit, i) ((lane & (bit)) ? RLSw(i) : RLCw(i))
        f2 Lu = SELu(32, 0) * SELu(16, 1);
        f2 Lw = SELw(32, 0) * SELw(16, 1);
        Lu = Lu * SELu(8, 2);   Lw = Lw * SELw(8, 2);
        Lu = Lu * SELu(4, 3);   Lw = Lw * SELw(4, 3);
        Lu = Lu * SELu(2, 4);   Lw = Lw * SELw(2, 4);
        Lu = Lu * SELu(1, 5);   Lw = Lw * SELw(1, 5);
        const f2 c6u = RLCu(6), s6u = RLSu(6), c7u = RLCu(7), s7u = RLSu(7);
        const f2 c6w = RLCw(6), s6w = RLSw(6), c7w = RLCw(7), s7w = RLSw(7);
        const f2 Lcu = Lu * c6u, Lsu = Lu * s6u;
        const f2 Lcw = Lw * c6w, Lsw = Lw * s6w;
        vv0u = Lcu * c7u; vv1u = Lcu * s7u; vv2u = Lsu * c7u; vv3u = Lsu * s7u;
        vv0w = Lcw * c7w; vv1w = Lcw * s7w; vv2w = Lsw * c7w; vv3w = Lsw * s7w;
    }

    // composed CNOT ring, source-side parity merge, both streams
#define RING2() {                                                            \
    const f2 z0u = psel ? vv2u : vv0u,  z0w = psel ? vv2w : vv0w;            \
    const f2 z1u = psel ? vv3u : vv1u,  z1w = psel ? vv3w : vv1w;            \
    const f2 z2u = psel ? vv1u : vv3u,  z2w = psel ? vv1w : vv3w;            \
    const f2 z3u = psel ? vv0u : vv2u,  z3w = psel ? vv0w : vv2w;            \
    vv0u = mk2(BPF(g4,  z0u.x), BPF(g4,  z0u.y));                            \
    vv0w = mk2(BPF(g4,  z0w.x), BPF(g4,  z0w.y));                            \
    vv1u = mk2(BPF(g4b, z1u.x), BPF(g4b, z1u.y));                            \
    vv1w = mk2(BPF(g4b, z1w.x), BPF(g4b, z1w.y));                            \
    vv2u = mk2(BPF(g4,  z2u.x), BPF(g4,  z2u.y));                            \
    vv2w = mk2(BPF(g4,  z2w.x), BPF(g4,  z2w.y));                            \
    vv3u = mk2(BPF(g4b, z3u.x), BPF(g4b, z3u.y));                            \
    vv3w = mk2(BPF(g4b, z3w.x), BPF(g4b, z3w.y)); }
    RING2()

#define RY_G2(ia, mask, PART) {                                              \
    const f2 cu = RLCu(ia), su = RLSu(ia);                                   \
    const f2 cw = RLCw(ia), sw = RLSw(ia);                                   \
    const f2 ssu = (lane & (mask)) ? su : -su;                               \
    const f2 ssw = (lane & (mask)) ? sw : -sw;                               \
    const f2 p0u = PART(vv0u), p0w = PART(vv0w);                             \
    const f2 p1u = PART(vv1u), p1w = PART(vv1w);                             \
    const f2 p2u = PART(vv2u), p2w = PART(vv2w);                             \
    const f2 p3u = PART(vv3u), p3w = PART(vv3w);                             \
    vv0u = FMA2(ssu, p0u, cu * vv0u);  vv0w = FMA2(ssw, p0w, cw * vv0w);     \
    vv1u = FMA2(ssu, p1u, cu * vv1u);  vv1w = FMA2(ssw, p1w, cw * vv1w);     \
    vv2u = FMA2(ssu, p2u, cu * vv2u);  vv2w = FMA2(ssw, p2w, cw * vv2w);     \
    vv3u = FMA2(ssu, p3u, cu * vv3u);  vv3w = FMA2(ssw, p3w, cw * vv3w); }

#define RY_SLOT1_2(ia) {                                                     \
    const f2 cu = RLCu(ia), su = RLSu(ia);                                   \
    const f2 cw = RLCw(ia), sw = RLSw(ia);                                   \
    const f2 n0u = cu*vv0u - su*vv2u, n2u = FMA2(su, vv0u, cu*vv2u);         \
    const f2 n0w = cw*vv0w - sw*vv2w, n2w = FMA2(sw, vv0w, cw*vv2w);         \
    const f2 n1u = cu*vv1u - su*vv3u, n3u = FMA2(su, vv1u, cu*vv3u);         \
    const f2 n1w = cw*vv1w - sw*vv3w, n3w = FMA2(sw, vv1w, cw*vv3w);         \
    vv0u = n0u; vv1u = n1u; vv2u = n2u; vv3u = n3u;                          \
    vv0w = n0w; vv1w = n1w; vv2w = n2w; vv3w = n3w; }

#define RY_SLOT0_2(ia) {                                                     \
    const f2 cu = RLCu(ia), su = RLSu(ia);                                   \
    const f2 cw = RLCw(ia), sw = RLSw(ia);                                   \
    const f2 n0u = cu*vv0u - su*vv1u, n1u = FMA2(su, vv0u, cu*vv1u);         \
    const f2 n0w = cw*vv0w - sw*vv1w, n1w = FMA2(sw, vv0w, cw*vv1w);         \
    const f2 n2u = cu*vv2u - su*vv3u, n3u = FMA2(su, vv2u, cu*vv3u);         \
    const f2 n2w = cw*vv2w - sw*vv3w, n3w = FMA2(sw, vv2w, cw*vv3w);         \
    vv0u = n0u; vv1u = n1u; vv2u = n2u; vv3u = n3u;                          \
    vv0w = n0w; vv1w = n1w; vv2w = n2w; vv3w = n3w; }

    // ---- cycles 1..3 ----
    #pragma unroll
    for (int cyc = 1; cyc < 4; ++cyc) {
        const int base = cyc * 8;
        RY_G2(base + 0, 32, PX32)
        RY_G2(base + 1, 16, PX16)
        RY_G2(base + 2,  8, PX8)
        RY_G2(base + 3,  4, PX4)
        RY_G2(base + 4,  2, PX2)
        RY_G2(base + 5,  1, PX1)
        RY_SLOT1_2(base + 6)
        RY_SLOT0_2(base + 7)
        RING2()
    }

    // ---- Phase 2: 10 CRX gates ----
    f2 rr0u = vv0u, rr1u = vv1u, rr2u = vv2u, rr3u = vv3u;
    f2 rr0w = vv0w, rr1w = vv1w, rr2w = vv2w, rr3w = vv3w;
    f2 ii0u = {0,0}, ii1u = {0,0}, ii2u = {0,0}, ii3u = {0,0};
    f2 ii0w = {0,0}, ii1w = {0,0}, ii2w = {0,0}, ii3w = {0,0};

#define CRX_PAIR(cS, sS, ct, rr, ii, PART, S)                                \
    { const f2 pr = PART(rr##S); const f2 pi = PART(ii##S);                  \
      const f2 nr = FMA2(sS, pi, cS*rr##S);                                  \
      const f2 ni = cS*ii##S - sS*pr;                                        \
      rr##S = ct ? nr : rr##S; ii##S = ct ? ni : ii##S; }

#define CRX_G2(gi, cmask, PART) {                                            \
    const f2 cu = RLCu(32 + (gi)), su = RLSu(32 + (gi));                     \
    const f2 cw = RLCw(32 + (gi)), sw = RLSw(32 + (gi));                     \
    const bool ct = (lane & (cmask)) != 0;                                   \
    CRX_PAIR(cu, su, ct, rr0, ii0, PART, u)                                  \
    CRX_PAIR(cw, sw, ct, rr0, ii0, PART, w)                                  \
    CRX_PAIR(cu, su, ct, rr1, ii1, PART, u)                                  \
    CRX_PAIR(cw, sw, ct, rr1, ii1, PART, w)                                  \
    CRX_PAIR(cu, su, ct, rr2, ii2, PART, u)                                  \
    CRX_PAIR(cw, sw, ct, rr2, ii2, PART, w)                                  \
    CRX_PAIR(cu, su, ct, rr3, ii3, PART, u)                                  \
    CRX_PAIR(cw, sw, ct, rr3, ii3, PART, w) }

    CRX_G2(0, 32, PX16)
    CRX_G2(1, 16, PX8)
    CRX_G2(2,  8, PX4)
    CRX_G2(3,  4, PX2)
    CRX_G2(4,  2, PX1)
    {   // gate 5: ctrl lane bit0, target amp bit1 (slot pairs (0,2),(1,3))
        const bool l0 = (lane & 1) != 0;
        const f2 cu = RLCu(37), su = RLSu(37);
        const f2 cw = RLCw(37), sw = RLSw(37);
        const f2 nr0u = FMA2(su, ii2u, cu*rr0u), ni0u = cu*ii0u - su*rr2u;
        const f2 nr0w = FMA2(sw, ii2w, cw*rr0w), ni0w = cw*ii0w - sw*rr2w;
        const f2 nr2u = FMA2(su, ii0u, cu*rr2u), ni2u = cu*ii2u - su*rr0u;
        const f2 nr2w = FMA2(sw, ii0w, cw*rr2w), ni2w = cw*ii2w - sw*rr0w;
        const f2 nr1u = FMA2(su, ii3u, cu*rr1u), ni1u = cu*ii1u - su*rr3u;
        const f2 nr1w = FMA2(sw, ii3w, cw*rr1w), ni1w = cw*ii1w - sw*rr3w;
        const f2 nr3u = FMA2(su, ii1u, cu*rr3u), ni3u = cu*ii3u - su*rr1u;
        const f2 nr3w = FMA2(sw, ii1w, cw*rr3w), ni3w = cw*ii3w - sw*rr1w;
        rr0u = l0?nr0u:rr0u; ii0u = l0?ni0u:ii0u; rr0w = l0?nr0w:rr0w; ii0w = l0?ni0w:ii0w;
        rr1u = l0?nr1u:rr1u; ii1u = l0?ni1u:ii1u; rr1w = l0?nr1w:rr1w; ii1w = l0?ni1w:ii1w;
        rr2u = l0?nr2u:rr2u; ii2u = l0?ni2u:ii2u; rr2w = l0?nr2w:rr2w; ii2w = l0?ni2w:ii2w;
        rr3u = l0?nr3u:rr3u; ii3u = l0?ni3u:ii3u; rr3w = l0?nr3w:rr3w; ii3w = l0?ni3w:ii3w;
    }
    {   // gate 6: ctrl slot bit1 (slots 2,3), target amp bit0
        const f2 cu = RLCu(38), su = RLSu(38);
        const f2 cw = RLCw(38), sw = RLSw(38);
        const f2 nr2u = FMA2(su, ii3u, cu*rr2u), ni2u = cu*ii2u - su*rr3u;
        const f2 nr2w = FMA2(sw, ii3w, cw*rr2w), ni2w = cw*ii2w - sw*rr3w;
        const f2 nr3u = FMA2(su, ii2u, cu*rr3u), ni3u = cu*ii3u - su*rr2u;
        const f2 nr3w = FMA2(sw, ii2w, cw*rr3w), ni3w = cw*ii3w - sw*rr2w;
        rr2u = nr2u; ii2u = ni2u; rr3u = nr3u; ii3u = ni3u;
        rr2w = nr2w; ii2w = ni2w; rr3w = nr3w; ii3w = ni3w;
    }
    {   // gate 7: ctrl slot bit0 (slots 1,3), target amp bit7 (lane^32)
        const f2 cu = RLCu(39), su = RLSu(39);
        const f2 cw = RLCw(39), sw = RLSw(39);
        const f2 pr1u = PX32(rr1u), pi1u = PX32(ii1u);
        const f2 pr1w = PX32(rr1w), pi1w = PX32(ii1w);
        const f2 pr3u = PX32(rr3u), pi3u = PX32(ii3u);
        const f2 pr3w = PX32(rr3w), pi3w = PX32(ii3w);
        rr1u = FMA2(su, pi1u, cu*rr1u); ii1u = cu*ii1u - su*pr1u;
        rr1w = FMA2(sw, pi1w, cw*rr1w); ii1w = cw*ii1w - sw*pr1w;
        rr3u = FMA2(su, pi3u, cu*rr3u); ii3u = cu*ii3u - su*pr3u;
        rr3w = FMA2(sw, pi3w, cw*rr3w); ii3w = cw*ii3w - sw*pr3w;
    }
    CRX_G2(8, 32, PX16)
    CRX_G2(9, 16, PX8)

    // ---- probabilities, <Z_3> (amp bit4 -> lane bit2), <Z_7> (amp bit0 -> slot0) ----
    const f2 p0u = FMA2(rr0u, rr0u, ii0u*ii0u), p1u = FMA2(rr1u, rr1u, ii1u*ii1u);
    const f2 p2u = FMA2(rr2u, rr2u, ii2u*ii2u), p3u = FMA2(rr3u, rr3u, ii3u*ii3u);
    const f2 p0w = FMA2(rr0w, rr0w, ii0w*ii0w), p1w = FMA2(rr1w, rr1w, ii1w*ii1w);
    const f2 p2w = FMA2(rr2w, rr2w, ii2w*ii2w), p3w = FMA2(rr3w, rr3w, ii3w*ii3w);
    const f2 sumu = (p0u + p1u) + (p2u + p3u);
    const f2 sumw = (p0w + p1w) + (p2w + p3w);
    f2 vq7u = (p0u + p2u) - (p1u + p3u);
    f2 vq7w = (p0w + p2w) - (p1w + p3w);
    f2 vq3u = (lane & 4) ? -sumu : sumu;
    f2 vq3w = (lane & 4) ? -sumw : sumw;
    vq3u = vq3u + PX1(vq3u);   vq7u = vq7u + PX1(vq7u);
    vq3w = vq3w + PX1(vq3w);   vq7w = vq7w + PX1(vq7w);
    vq3u = vq3u + PX2(vq3u);   vq7u = vq7u + PX2(vq7u);
    vq3w = vq3w + PX2(vq3w);   vq7w = vq7w + PX2(vq7w);
    vq3u = vq3u + PX4(vq3u);   vq7u = vq7u + PX4(vq7u);
    vq3w = vq3w + PX4(vq3w);   vq7w = vq7w + PX4(vq7w);
    vq3u = vq3u + PX8(vq3u);   vq7u = vq7u + PX8(vq7u);
    vq3w = vq3w + PX8(vq3w);   vq7w = vq7w + PX8(vq7w);
    vq3u = vq3u + PX16(vq3u);  vq7u = vq7u + PX16(vq7u);
    vq3w = vq3w + PX16(vq3w);  vq7w = vq7w + PX16(vq7w);
    vq3u = vq3u + PX32(vq3u);  vq7u = vq7u + PX32(vq7u);
    vq3w = vq3w + PX32(vq3w);  vq7w = vq7w + PX32(vq7w);

    // ---- MLP: lane u (<10) computes hidden unit u for all 4 states ----
    float wa = 0.f, wb = 0.f, bb = 0.f, wc = 0.f;
    if (lane < 10) {
        wa = w1[2 * lane];
        wb = w1[2 * lane + 1];
        bb = b1[lane];
        wc = w2[lane];
    }
    const f2 wa2 = mk2(wa, wa), wb2 = mk2(wb, wb), bb2 = mk2(bb, bb);
    const f2 zu = FMA2(wa2, vq3u, FMA2(wb2, vq7u, bb2));
    const f2 zw = FMA2(wa2, vq3w, FMA2(wb2, vq7w, bb2));
    const f2 eu = mk2(__expf(2.0f * zu.x), __expf(2.0f * zu.y));
    const f2 ew = mk2(__expf(2.0f * zw.x), __expf(2.0f * zw.y));
    const f2 hu = mk2(1.0f - 2.0f * __builtin_amdgcn_rcpf(eu.x + 1.0f),
                      1.0f - 2.0f * __builtin_amdgcn_rcpf(eu.y + 1.0f));
    const f2 hw = mk2(1.0f - 2.0f * __builtin_amdgcn_rcpf(ew.x + 1.0f),
                      1.0f - 2.0f * __builtin_amdgcn_rcpf(ew.y + 1.0f));
    f2 au = mk2(wc, wc) * hu;
    f2 aw = mk2(wc, wc) * hw;
    au = au + PX1(au);  aw = aw + PX1(aw);
    au = au + PX2(au);  aw = aw + PX2(aw);
    au = au + PX4(au);  aw = aw + PX4(aw);
    au = au + PX8(au);  aw = aw + PX8(aw);   // sum over lanes 0..15
    if (lane == 0) {
        const float bias = b2[0];
        out[bA + 0] = __builtin_amdgcn_rcpf(1.0f + __expf(-(au.x + bias)));
        out[bA + 1] = __builtin_amdgcn_rcpf(1.0f + __expf(-(au.y + bias)));
        out[bA + 2] = __builtin_amdgcn_rcpf(1.0f + __expf(-(aw.x + bias)));
        out[bA + 3] = __builtin_amdgcn_rcpf(1.0f + __expf(-(aw.y + bias)));
    }
}

extern "C" void kernel_launch(void* const* d_in, const int* in_sizes, int n_in,
                              void* d_out, int out_size, void* d_ws, size_t ws_size,
                              hipStream_t stream) {
    const float* x         = (const float*)d_in[0];
    const float* crx_theta = (const float*)d_in[1];
    const float* w1        = (const float*)d_in[2];
    const float* b1        = (const float*)d_in[3];
    const float* w2        = (const float*)d_in[4];
    const float* b2        = (const float*)d_in[5];
    float* out = (float*)d_out;

    const int B = in_sizes[0] / 32;  // x is (B, 4, 8)
    vqcnn_wave<<<B / 16, 256, 0, stream>>>(x, crx_theta, w1, b1, w2, b2, out);
}

// Round 9
// 75.796 us; speedup vs baseline: 1.1451x; 1.0884x over previous
//
#include <hip/hip_runtime.h>
#include <math.h>

// Two states per wave, packed as f16x2 (state A = .x, B = .y of each 32-bit
// reg): v_pk_fma_f16 is full-rate, so f16 packing halves VALU cycles AND
// halves bperm/DPP/readlane count per state (one b32 op moves both states).
// Qubit relabeling (rotate 5 around the CNOT ring): qubit q -> amp bit
// 7-((q+5)%8): q0->b2,q1->b1,q2->b0,q3->b7,q4->b6,q5->b5,q6->b4,q7->b3.
// Amp bits 7..2 = lane bits 5..0, bits 1..0 = slot (4 regs).
// CRX gates 0,1,8,9 become slot-local (free); only gates 2 (half, xor32) and
// 3 (full, xor16) need bperm. Measured: q3->b7 (lane bit5), q7->b3 (lane bit1).
// Ring (derived, R8 ERRATA): src_lane = gray(lane) ^ (slot0?32:0); the
// source-side reg-select predicate is SOURCE LANE BIT 0 (qp(dest) = d0^d1
// propagated through dest = gray^-1(L) collapses to L&1). R8 wrongly used
// qp(source) = L0^L1 -> half the lanes fetched the wrong register.
// Init (cycle-0 product state) and epilogue (reduction + MLP) in f32.

typedef _Float16 h2 __attribute__((ext_vector_type(2)));

#define H2I(v) __builtin_bit_cast(int, (v))
#define I2H(v) __builtin_bit_cast(h2, (v))
#define RLF(v, i) __int_as_float(__builtin_amdgcn_readlane(__float_as_int(v), (i)))
#define RLH(v, i) I2H(__builtin_amdgcn_readlane(H2I(v), (i)))
#define BPH(a, v) I2H(__builtin_amdgcn_ds_bpermute((a), H2I(v)))
#define BPFS(a, v) __int_as_float(__builtin_amdgcn_ds_bpermute((a), __float_as_int(v)))
#define DPPH(v, ctrl) I2H(__builtin_amdgcn_update_dpp(0, H2I(v), (ctrl), 0xf, 0xf, true))
#define DPPF(v, ctrl) __uint_as_float((unsigned)__builtin_amdgcn_update_dpp( \
    0, (int)__float_as_uint(v), (ctrl), 0xf, 0xf, true))
#define NEGH(v) I2H(H2I(v) ^ 0x80008000)
#define SELH(c, a, b) I2H((c) ? H2I(a) : H2I(b))
#define FMH(a, b, c) __builtin_elementwise_fma((a), (b), (c))

#define PX1H(v)  DPPH((v), 0xB1)               // lane^1
#define PX2H(v)  DPPH((v), 0x4E)               // lane^2
#define PX4H(v)  DPPH(DPPH((v), 0x141), 0x1B)  // lane^4 (half_mirror o quad)
#define PX8H(v)  DPPH((v), 0x128)              // lane^8 (row_ror:8)
#define BP16(v)  BPH(a16, (v))
#define BP32(v)  BPH(a32, (v))
#define PX1S(v)  DPPF((v), 0xB1)
#define PX2S(v)  DPPF((v), 0x4E)
#define PX4S(v)  DPPF(DPPF((v), 0x141), 0x1B)
#define PX8S(v)  DPPF((v), 0x128)

__device__ __forceinline__ h2 mkh(float a, float b) {
    h2 r; r.x = (_Float16)a; r.y = (_Float16)b; return r;
}

__global__ __launch_bounds__(256, 8) void vqcnn_wave(
    const float* __restrict__ x,          // (B, 4, 8)
    const float* __restrict__ crx_theta,  // (10,)
    const float* __restrict__ w1,         // (10, 2)
    const float* __restrict__ b1,         // (10,)
    const float* __restrict__ w2,         // (1, 10)
    const float* __restrict__ b2,         // (1,)
    float* __restrict__ out)              // (B, 1)
{
    const int lane = threadIdx.x & 63;
    const int bA   = blockIdx.x * 8 + (threadIdx.x >> 6) * 2;
    const int bB   = bA + 1;

    // angle tables: lanes 0..31 RY (idx = cyc*8+q), lanes 32..41 CRX
    float cvA, svA, cvB, svB;
    {
        float aA = 0.f, aB = 0.f;
        if (lane < 32)      { aA = x[bA * 32 + lane]; aB = x[bB * 32 + lane]; }
        else if (lane < 42) { aA = aB = crx_theta[lane - 32]; }
        __sincosf(0.5f * aA, &svA, &cvA);
        __sincosf(0.5f * aB, &svB, &cvB);
    }
    const h2 cvP = mkh(cvA, cvB);
    const h2 svP = mkh(svA, svB);

    // bperm byte addresses
    const int a16 = (lane ^ 16) << 2;
    const int a32 = (lane ^ 32) << 2;
    const int g0  = lane ^ (lane >> 1);      // ring src lane (gray code)
    const int aE  = g0 << 2;                 // even dest slots (s0=0)
    const int aO  = (g0 ^ 32) << 2;          // odd dest slots  (s0=1)
    const bool l0r = (lane & 1) != 0;        // ring source-select predicate

    // ---- cycle 0: product state in f32, then pack ----
    h2 vv0, vv1, vv2, vv3;
    {
        float LA = (lane & 32) ? RLF(svA, 3) : RLF(cvA, 3);  // q3 -> b7
        float LB = (lane & 32) ? RLF(svB, 3) : RLF(cvB, 3);
        LA *= (lane & 16) ? RLF(svA, 4) : RLF(cvA, 4);       // q4 -> b6
        LB *= (lane & 16) ? RLF(svB, 4) : RLF(cvB, 4);
        LA *= (lane &  8) ? RLF(svA, 5) : RLF(cvA, 5);       // q5 -> b5
        LB *= (lane &  8) ? RLF(svB, 5) : RLF(cvB, 5);
        LA *= (lane &  4) ? RLF(svA, 6) : RLF(cvA, 6);       // q6 -> b4
        LB *= (lane &  4) ? RLF(svB, 6) : RLF(cvB, 6);
        LA *= (lane &  2) ? RLF(svA, 7) : RLF(cvA, 7);       // q7 -> b3
        LB *= (lane &  2) ? RLF(svB, 7) : RLF(cvB, 7);
        LA *= (lane &  1) ? RLF(svA, 0) : RLF(cvA, 0);       // q0 -> b2
        LB *= (lane &  1) ? RLF(svB, 0) : RLF(cvB, 0);
        const float c1A = RLF(cvA, 1), s1A = RLF(svA, 1);    // q1 -> b1 (slot1)
        const float c2A = RLF(cvA, 2), s2A = RLF(svA, 2);    // q2 -> b0 (slot0)
        const float c1B = RLF(cvB, 1), s1B = RLF(svB, 1);
        const float c2B = RLF(cvB, 2), s2B = RLF(svB, 2);
        vv0 = mkh(LA * c1A * c2A, LB * c1B * c2B);
        vv1 = mkh(LA * c1A * s2A, LB * c1B * s2B);
        vv2 = mkh(LA * s1A * c2A, LB * s1B * c2B);
        vv3 = mkh(LA * s1A * s2A, LB * s1B * s2B);
    }

    // composed CNOT ring: source-side merged gather, predicate = lane&1
#define RINGH() {                                                            \
    const h2 z0 = SELH(l0r, vv2, vv0);                                       \
    const h2 z1 = SELH(l0r, vv3, vv1);                                       \
    const h2 z2 = SELH(l0r, vv1, vv3);                                       \
    const h2 z3 = SELH(l0r, vv0, vv2);                                       \
    vv0 = BPH(aE, z0); vv1 = BPH(aO, z1);                                    \
    vv2 = BPH(aE, z2); vv3 = BPH(aO, z3); }
    RINGH()

    // RY lane-exchange gate: new = c*v + (lane&mask ? s : -s) * partner
#define RY_L(ia, mask, EX) {                                                 \
    const h2 c = RLH(cvP, (ia)), s = RLH(svP, (ia));                         \
    const h2 sn = SELH((lane & (mask)) != 0, s, NEGH(s));                    \
    const h2 p0 = EX(vv0), p1 = EX(vv1);                                     \
    const h2 p2 = EX(vv2), p3 = EX(vv3);                                     \
    vv0 = FMH(sn, p0, c * vv0); vv1 = FMH(sn, p1, c * vv1);                  \
    vv2 = FMH(sn, p2, c * vv2); vv3 = FMH(sn, p3, c * vv3); }

    // RY on slot bit1 (q1): pairs (0,2),(1,3)
#define RY_S1(ia) {                                                          \
    const h2 c = RLH(cvP, (ia)), s = RLH(svP, (ia)), ns = NEGH(s);           \
    const h2 n0 = FMH(ns, vv2, c * vv0), n2 = FMH(s, vv0, c * vv2);          \
    const h2 n1 = FMH(ns, vv3, c * vv1), n3 = FMH(s, vv1, c * vv3);          \
    vv0 = n0; vv1 = n1; vv2 = n2; vv3 = n3; }

    // RY on slot bit0 (q2): pairs (0,1),(2,3)
#define RY_S0(ia) {                                                          \
    const h2 c = RLH(cvP, (ia)), s = RLH(svP, (ia)), ns = NEGH(s);           \
    const h2 n0 = FMH(ns, vv1, c * vv0), n1 = FMH(s, vv0, c * vv1);          \
    const h2 n2 = FMH(ns, vv3, c * vv2), n3 = FMH(s, vv2, c * vv3);          \
    vv0 = n0; vv1 = n1; vv2 = n2; vv3 = n3; }

    // ---- cycles 1..3: 8 RY + ring (real arithmetic, f16 packed) ----
    #pragma unroll
    for (int cyc = 1; cyc < 4; ++cyc) {
        const int base = cyc * 8;
        RY_L(base + 0,  1, PX1H)   // q0 -> b2 (lane0)
        RY_S1(base + 1)            // q1 -> b1 (slot1)
        RY_S0(base + 2)            // q2 -> b0 (slot0)
        RY_L(base + 3, 32, BP32)   // q3 -> b7 (lane5)
        RY_L(base + 4, 16, BP16)   // q4 -> b6 (lane4)
        RY_L(base + 5,  8, PX8H)   // q5 -> b5
        RY_L(base + 6,  4, PX4H)   // q6 -> b4
        RY_L(base + 7,  2, PX2H)   // q7 -> b3
        RINGH()
    }

    // ---- Phase 2: 10 CRX gates (complex, f16 packed) ----
    h2 rr0 = vv0, rr1 = vv1, rr2 = vv2, rr3 = vv3;
    h2 ii0 = I2H(0), ii1 = I2H(0), ii2 = I2H(0), ii3 = I2H(0);

#define CRX_L(gi, cmask, EX) {                                               \
    const h2 c = RLH(cvP, 32 + (gi)), s = RLH(svP, 32 + (gi)), ns = NEGH(s); \
    const bool ct = (lane & (cmask)) != 0;                                   \
    h2 pr, pi, nr, ni;                                                       \
    pr = EX(rr0); pi = EX(ii0);                                              \
    nr = FMH(s, pi, c * rr0); ni = FMH(ns, pr, c * ii0);                     \
    rr0 = SELH(ct, nr, rr0); ii0 = SELH(ct, ni, ii0);                        \
    pr = EX(rr1); pi = EX(ii1);                                              \
    nr = FMH(s, pi, c * rr1); ni = FMH(ns, pr, c * ii1);                     \
    rr1 = SELH(ct, nr, rr1); ii1 = SELH(ct, ni, ii1);                        \
    pr = EX(rr2); pi = EX(ii2);                                              \
    nr = FMH(s, pi, c * rr2); ni = FMH(ns, pr, c * ii2);                     \
    rr2 = SELH(ct, nr, rr2); ii2 = SELH(ct, ni, ii2);                        \
    pr = EX(rr3); pi = EX(ii3);                                              \
    nr = FMH(s, pi, c * rr3); ni = FMH(ns, pr, c * ii3);                     \
    rr3 = SELH(ct, nr, rr3); ii3 = SELH(ct, ni, ii3); }

    // gates 0 & 8: ctrl b2 (lane&1), target b1 = slot bit1: pairs (0,2),(1,3)
#define CRX_SLOT1(gi) {                                                      \
    const h2 c = RLH(cvP, 32 + (gi)), s = RLH(svP, 32 + (gi)), ns = NEGH(s); \
    const bool ct = (lane & 1) != 0;                                         \
    const h2 nr0 = FMH(s, ii2, c * rr0), ni0 = FMH(ns, rr2, c * ii0);        \
    const h2 nr2 = FMH(s, ii0, c * rr2), ni2 = FMH(ns, rr0, c * ii2);        \
    const h2 nr1 = FMH(s, ii3, c * rr1), ni1 = FMH(ns, rr3, c * ii1);        \
    const h2 nr3 = FMH(s, ii1, c * rr3), ni3 = FMH(ns, rr1, c * ii3);        \
    rr0 = SELH(ct, nr0, rr0); ii0 = SELH(ct, ni0, ii0);                      \
    rr1 = SELH(ct, nr1, rr1); ii1 = SELH(ct, ni1, ii1);                      \
    rr2 = SELH(ct, nr2, rr2); ii2 = SELH(ct, ni2, ii2);                      \
    rr3 = SELH(ct, nr3, rr3); ii3 = SELH(ct, ni3, ii3); }

    // gates 1 & 9: ctrl slot bit1 (regs 2,3), target slot bit0: pair (2,3)
#define CRX_SLOT0(gi) {                                                      \
    const h2 c = RLH(cvP, 32 + (gi)), s = RLH(svP, 32 + (gi)), ns = NEGH(s); \
    const h2 nr2 = FMH(s, ii3, c * rr2), ni2 = FMH(ns, rr3, c * ii2);        \
    const h2 nr3 = FMH(s, ii2, c * rr3), ni3 = FMH(ns, rr2, c * ii3);        \
    rr2 = nr2; ii2 = ni2; rr3 = nr3; ii3 = ni3; }

    CRX_SLOT1(0)           // i=0: c=q0(b2), t=q1(b1)
    CRX_SLOT0(1)           // i=1: c=q1(b1), t=q2(b0)
    {   // i=2: c=q2(b0: slots 1,3), t=q3(b7: lane^32) — half-width bperm
        const h2 c = RLH(cvP, 34), s = RLH(svP, 34), ns = NEGH(s);
        const h2 pr1 = BP32(rr1), pi1 = BP32(ii1);
        const h2 pr3 = BP32(rr3), pi3 = BP32(ii3);
        rr1 = FMH(s, pi1, c * rr1); ii1 = FMH(ns, pr1, c * ii1);
        rr3 = FMH(s, pi3, c * rr3); ii3 = FMH(ns, pr3, c * ii3);
    }
    CRX_L(3, 32, BP16)     // i=3: c=b7, t=b6
    CRX_L(4, 16, PX8H)     // i=4: c=b6, t=b5
    CRX_L(5,  8, PX4H)     // i=5: c=b5, t=b4
    CRX_L(6,  4, PX2H)     // i=6: c=b4, t=b3
    CRX_L(7,  2, PX1H)     // i=7: c=b3, t=b2
    CRX_SLOT1(8)           // i=8: same as i=0
    CRX_SLOT0(9)           // i=9: same as i=1

    // ---- probs (f16) -> f32 epilogue ----
    const h2 pp0 = FMH(rr0, rr0, ii0 * ii0);
    const h2 pp1 = FMH(rr1, rr1, ii1 * ii1);
    const h2 pp2 = FMH(rr2, rr2, ii2 * ii2);
    const h2 pp3 = FMH(rr3, rr3, ii3 * ii3);
    const h2 ap  = (pp0 + pp1) + (pp2 + pp3);
    const float aA = (float)ap.x, aB = (float)ap.y;
    // q3 -> b7 (lane bit5), q7 -> b3 (lane bit1)
    float z3A = (lane & 32) ? -aA : aA, z3B = (lane & 32) ? -aB : aB;
    float z7A = (lane &  2) ? -aA : aA, z7B = (lane &  2) ? -aB : aB;
    z3A += PX1S(z3A); z3B += PX1S(z3B); z7A += PX1S(z7A); z7B += PX1S(z7B);
    z3A += PX2S(z3A); z3B += PX2S(z3B); z7A += PX2S(z7A); z7B += PX2S(z7B);
    z3A += PX4S(z3A); z3B += PX4S(z3B); z7A += PX4S(z7A); z7B += PX4S(z7B);
    z3A += PX8S(z3A); z3B += PX8S(z3B); z7A += PX8S(z7A); z7B += PX8S(z7B);
    z3A += BPFS(a16, z3A); z3B += BPFS(a16, z3B);
    z7A += BPFS(a16, z7A); z7B += BPFS(a16, z7B);
    z3A += BPFS(a32, z3A); z3B += BPFS(a32, z3B);
    z7A += BPFS(a32, z7A); z7B += BPFS(a32, z7B);

    // ---- MLP: lane u (<10) computes hidden unit u for both states ----
    float wa = 0.f, wb = 0.f, bb = 0.f, wc = 0.f;
    if (lane < 10) {
        wa = w1[2 * lane];
        wb = w1[2 * lane + 1];
        bb = b1[lane];
        wc = w2[lane];
    }
    const float zA = fmaf(wa, z3A, fmaf(wb, z7A, bb));
    const float zB = fmaf(wa, z3B, fmaf(wb, z7B, bb));
    const float eA = __expf(2.0f * zA), eB = __expf(2.0f * zB);
    const float hA = 1.0f - 2.0f * __builtin_amdgcn_rcpf(eA + 1.0f);
    const float hB = 1.0f - 2.0f * __builtin_amdgcn_rcpf(eB + 1.0f);
    float accA = wc * hA, accB = wc * hB;    // lanes >=10 contribute 0
    accA += PX1S(accA); accB += PX1S(accB);
    accA += PX2S(accA); accB += PX2S(accB);
    accA += PX4S(accA); accB += PX4S(accB);
    accA += PX8S(accA); accB += PX8S(accB);  // sum over lanes 0..15
    if (lane == 0) {
        const float bias = b2[0];
        out[bA] = __builtin_amdgcn_rcpf(1.0f + __expf(-(accA + bias)));
        out[bB] = __builtin_amdgcn_rcpf(1.0f + __expf(-(accB + bias)));
    }
}

extern "C" void kernel_launch(void* const* d_in, const int* in_sizes, int n_in,
                              void* d_out, int out_size, void* d_ws, size_t ws_size,
                              hipStream_t stream) {
    const float* x         = (const float*)d_in[0];
    const float* crx_theta = (const float*)d_in[1];
    const float* w1        = (const float*)d_in[2];
    const float* b1        = (const float*)d_in[3];
    const float* w2        = (const float*)d_in[4];
    const float* b2        = (const float*)d_in[5];
    float* out = (float*)d_out;

    const int B = in_sizes[0] / 32;  // x is (B, 4, 8)
    vqcnn_wave<<<B / 8, 256, 0, stream>>>(x, crx_theta, w1, b1, w2, b2, out);
}

// Round 11
// 75.383 us; speedup vs baseline: 1.1514x; 1.0055x over previous
//
#include <hip/hip_runtime.h>
#include <math.h>

// Two states per wave, packed f16x2 (A=.x, B=.y). Base = R9 (verified pass,
// absmax 3.9e-3) + CRX de-selection from R10 (provably exact: for non-ctrl
// lanes c'=1, s'=0 gives fma(0,p,1*v)=v bit-identical; removes 8 dependent
// cndmasks per CRX gate from the serial critical path).
// R10's v_permlane{16,32}_swap pair idiom is DROPPED: return-order ambiguity
// of the builtin produced a pure register swap (no lane exchange) on HW;
// two failed rounds, not disambiguable without a wasted bench. bperm stays.
// Layout (verified): qubit q -> amp bit 7-((q+5)%8); amp bits 7..2 = lane
// bits 5..0, bits 1..0 = slot. Ring: src_lane = gray(lane) ^ (slot0?32:0),
// source-side reg-select predicate = SOURCE lane bit 0 (R8 errata).
// Measured: q3 -> b7 (lane bit5), q7 -> b3 (lane bit1).

typedef _Float16 h2 __attribute__((ext_vector_type(2)));

#define H2I(v) __builtin_bit_cast(int, (v))
#define I2H(v) __builtin_bit_cast(h2, (v))
#define RLF(v, i) __int_as_float(__builtin_amdgcn_readlane(__float_as_int(v), (i)))
#define RLH(v, i) I2H(__builtin_amdgcn_readlane(H2I(v), (i)))
#define BPH(a, v) I2H(__builtin_amdgcn_ds_bpermute((a), H2I(v)))
#define BPFS(a, v) __int_as_float(__builtin_amdgcn_ds_bpermute((a), __float_as_int(v)))
#define DPPH(v, ctrl) I2H(__builtin_amdgcn_update_dpp(0, H2I(v), (ctrl), 0xf, 0xf, true))
#define DPPF(v, ctrl) __uint_as_float((unsigned)__builtin_amdgcn_update_dpp( \
    0, (int)__float_as_uint(v), (ctrl), 0xf, 0xf, true))
#define NEGH(v) I2H(H2I(v) ^ 0x80008000)
#define SELH(c, a, b) I2H((c) ? H2I(a) : H2I(b))
#define FMH(a, b, c) __builtin_elementwise_fma((a), (b), (c))
#define HONE  I2H(0x3C003C00)
#define HZERO I2H(0)

#define PX1H(v)  DPPH((v), 0xB1)               // lane^1
#define PX2H(v)  DPPH((v), 0x4E)               // lane^2
#define PX4H(v)  DPPH(DPPH((v), 0x141), 0x1B)  // lane^4 (half_mirror o quad)
#define PX8H(v)  DPPH((v), 0x128)              // lane^8 (row_ror:8)
#define BP16(v)  BPH(a16, (v))
#define BP32(v)  BPH(a32, (v))
#define PX1S(v)  DPPF((v), 0xB1)
#define PX2S(v)  DPPF((v), 0x4E)
#define PX4S(v)  DPPF(DPPF((v), 0x141), 0x1B)
#define PX8S(v)  DPPF((v), 0x128)

__device__ __forceinline__ h2 mkh(float a, float b) {
    h2 r; r.x = (_Float16)a; r.y = (_Float16)b; return r;
}

__global__ __launch_bounds__(256, 8) void vqcnn_wave(
    const float* __restrict__ x,          // (B, 4, 8)
    const float* __restrict__ crx_theta,  // (10,)
    const float* __restrict__ w1,         // (10, 2)
    const float* __restrict__ b1,         // (10,)
    const float* __restrict__ w2,         // (1, 10)
    const float* __restrict__ b2,         // (1,)
    float* __restrict__ out)              // (B, 1)
{
    const int lane = threadIdx.x & 63;
    const int bA   = blockIdx.x * 8 + (threadIdx.x >> 6) * 2;
    const int bB   = bA + 1;

    // angle tables: lanes 0..31 RY (idx = cyc*8+q), lanes 32..41 CRX
    float cvA, svA, cvB, svB;
    {
        float aA = 0.f, aB = 0.f;
        if (lane < 32)      { aA = x[bA * 32 + lane]; aB = x[bB * 32 + lane]; }
        else if (lane < 42) { aA = aB = crx_theta[lane - 32]; }
        __sincosf(0.5f * aA, &svA, &cvA);
        __sincosf(0.5f * aB, &svB, &cvB);
    }
    const h2 cvP = mkh(cvA, cvB);
    const h2 svP = mkh(svA, svB);

    // bperm byte addresses
    const int a16 = (lane ^ 16) << 2;
    const int a32 = (lane ^ 32) << 2;
    const int g0  = lane ^ (lane >> 1);      // ring src lane (gray code)
    const int aE  = g0 << 2;                 // even dest slots (s0=0)
    const int aO  = (g0 ^ 32) << 2;          // odd dest slots  (s0=1)
    const bool l0r = (lane & 1) != 0;        // ring source-select predicate

    // ---- cycle 0: product state in f32, then pack ----
    h2 vv0, vv1, vv2, vv3;
    {
        float LA = (lane & 32) ? RLF(svA, 3) : RLF(cvA, 3);  // q3 -> b7
        float LB = (lane & 32) ? RLF(svB, 3) : RLF(cvB, 3);
        LA *= (lane & 16) ? RLF(svA, 4) : RLF(cvA, 4);       // q4 -> b6
        LB *= (lane & 16) ? RLF(svB, 4) : RLF(cvB, 4);
        LA *= (lane &  8) ? RLF(svA, 5) : RLF(cvA, 5);       // q5 -> b5
        LB *= (lane &  8) ? RLF(svB, 5) : RLF(cvB, 5);
        LA *= (lane &  4) ? RLF(svA, 6) : RLF(cvA, 6);       // q6 -> b4
        LB *= (lane &  4) ? RLF(svB, 6) : RLF(cvB, 6);
        LA *= (lane &  2) ? RLF(svA, 7) : RLF(cvA, 7);       // q7 -> b3
        LB *= (lane &  2) ? RLF(svB, 7) : RLF(cvB, 7);
        LA *= (lane &  1) ? RLF(svA, 0) : RLF(cvA, 0);       // q0 -> b2
        LB *= (lane &  1) ? RLF(svB, 0) : RLF(cvB, 0);
        const float c1A = RLF(cvA, 1), s1A = RLF(svA, 1);    // q1 -> b1 (slot1)
        const float c2A = RLF(cvA, 2), s2A = RLF(svA, 2);    // q2 -> b0 (slot0)
        const float c1B = RLF(cvB, 1), s1B = RLF(svB, 1);
        const float c2B = RLF(cvB, 2), s2B = RLF(svB, 2);
        vv0 = mkh(LA * c1A * c2A, LB * c1B * c2B);
        vv1 = mkh(LA * c1A * s2A, LB * c1B * s2B);
        vv2 = mkh(LA * s1A * c2A, LB * s1B * c2B);
        vv3 = mkh(LA * s1A * s2A, LB * s1B * s2B);
    }

    // composed CNOT ring: source-side merged gather, predicate = lane&1
#define RINGH() {                                                            \
    const h2 z0 = SELH(l0r, vv2, vv0);                                       \
    const h2 z1 = SELH(l0r, vv3, vv1);                                       \
    const h2 z2 = SELH(l0r, vv1, vv3);                                       \
    const h2 z3 = SELH(l0r, vv0, vv2);                                       \
    vv0 = BPH(aE, z0); vv1 = BPH(aO, z1);                                    \
    vv2 = BPH(aE, z2); vv3 = BPH(aO, z3); }
    RINGH()

    // RY lane-exchange gate: new = c*v + (lane&mask ? s : -s) * partner
#define RY_L(ia, mask, EX) {                                                 \
    const h2 c = RLH(cvP, (ia)), s = RLH(svP, (ia));                         \
    const h2 sn = SELH((lane & (mask)) != 0, s, NEGH(s));                    \
    const h2 p0 = EX(vv0), p1 = EX(vv1);                                     \
    const h2 p2 = EX(vv2), p3 = EX(vv3);                                     \
    vv0 = FMH(sn, p0, c * vv0); vv1 = FMH(sn, p1, c * vv1);                  \
    vv2 = FMH(sn, p2, c * vv2); vv3 = FMH(sn, p3, c * vv3); }

    // RY on slot bit1 (q1): pairs (0,2),(1,3)
#define RY_S1(ia) {                                                          \
    const h2 c = RLH(cvP, (ia)), s = RLH(svP, (ia)), ns = NEGH(s);           \
    const h2 n0 = FMH(ns, vv2, c * vv0), n2 = FMH(s, vv0, c * vv2);          \
    const h2 n1 = FMH(ns, vv3, c * vv1), n3 = FMH(s, vv1, c * vv3);          \
    vv0 = n0; vv1 = n1; vv2 = n2; vv3 = n3; }

    // RY on slot bit0 (q2): pairs (0,1),(2,3)
#define RY_S0(ia) {                                                          \
    const h2 c = RLH(cvP, (ia)), s = RLH(svP, (ia)), ns = NEGH(s);           \
    const h2 n0 = FMH(ns, vv1, c * vv0), n1 = FMH(s, vv0, c * vv1);          \
    const h2 n2 = FMH(ns, vv3, c * vv2), n3 = FMH(s, vv2, c * vv3);          \
    vv0 = n0; vv1 = n1; vv2 = n2; vv3 = n3; }

    // ---- cycles 1..3: 8 RY + ring (real arithmetic, f16 packed) ----
    #pragma unroll
    for (int cyc = 1; cyc < 4; ++cyc) {
        const int base = cyc * 8;
        RY_L(base + 0,  1, PX1H)   // q0 -> b2 (lane0)
        RY_S1(base + 1)            // q1 -> b1 (slot1)
        RY_S0(base + 2)            // q2 -> b0 (slot0)
        RY_L(base + 3, 32, BP32)   // q3 -> b7 (lane5)
        RY_L(base + 4, 16, BP16)   // q4 -> b6 (lane4)
        RY_L(base + 5,  8, PX8H)   // q5 -> b5
        RY_L(base + 6,  4, PX4H)   // q6 -> b4
        RY_L(base + 7,  2, PX2H)   // q7 -> b3
        RINGH()
    }

    // ---- Phase 2: 10 CRX gates (complex, f16 packed, de-selected coeffs) ----
    h2 rr0 = vv0, rr1 = vv1, rr2 = vv2, rr3 = vv3;
    h2 ii0 = HZERO, ii1 = HZERO, ii2 = HZERO, ii3 = HZERO;

    // CRX with exchange EX; ctrl folded into coefficients (c'=ct?c:1, s'=ct?s:0)
#define CRX_G(gi, cmask, EX) {                                               \
    const bool ct = (lane & (cmask)) != 0;                                   \
    const h2 c = SELH(ct, RLH(cvP, 32 + (gi)), HONE);                        \
    const h2 s = SELH(ct, RLH(svP, 32 + (gi)), HZERO);                       \
    const h2 ns = NEGH(s);                                                   \
    const h2 pr0 = EX(rr0), pi0 = EX(ii0);                                   \
    const h2 pr1 = EX(rr1), pi1 = EX(ii1);                                   \
    const h2 pr2 = EX(rr2), pi2 = EX(ii2);                                   \
    const h2 pr3 = EX(rr3), pi3 = EX(ii3);                                   \
    rr0 = FMH(s, pi0, c * rr0); ii0 = FMH(ns, pr0, c * ii0);                 \
    rr1 = FMH(s, pi1, c * rr1); ii1 = FMH(ns, pr1, c * ii1);                 \
    rr2 = FMH(s, pi2, c * rr2); ii2 = FMH(ns, pr2, c * ii2);                 \
    rr3 = FMH(s, pi3, c * rr3); ii3 = FMH(ns, pr3, c * ii3); }

    // gates 0 & 8: ctrl b2 (lane&1), target slot bit1: pairs (0,2),(1,3)
#define CRX_SLOT1(gi) {                                                      \
    const bool ct = (lane & 1) != 0;                                         \
    const h2 c = SELH(ct, RLH(cvP, 32 + (gi)), HONE);                        \
    const h2 s = SELH(ct, RLH(svP, 32 + (gi)), HZERO);                       \
    const h2 ns = NEGH(s);                                                   \
    const h2 nr0 = FMH(s, ii2, c * rr0), ni0 = FMH(ns, rr2, c * ii0);        \
    const h2 nr2 = FMH(s, ii0, c * rr2), ni2 = FMH(ns, rr0, c * ii2);        \
    const h2 nr1 = FMH(s, ii3, c * rr1), ni1 = FMH(ns, rr3, c * ii1);        \
    const h2 nr3 = FMH(s, ii1, c * rr3), ni3 = FMH(ns, rr1, c * ii3);        \
    rr0 = nr0; ii0 = ni0; rr1 = nr1; ii1 = ni1;                              \
    rr2 = nr2; ii2 = ni2; rr3 = nr3; ii3 = ni3; }

    // gates 1 & 9: ctrl slot bit1 (regs 2,3 always ctrl'd), target slot bit0
#define CRX_SLOT0(gi) {                                                      \
    const h2 c = RLH(cvP, 32 + (gi)), s = RLH(svP, 32 + (gi)), ns = NEGH(s); \
    const h2 nr2 = FMH(s, ii3, c * rr2), ni2 = FMH(ns, rr3, c * ii2);        \
    const h2 nr3 = FMH(s, ii2, c * rr3), ni3 = FMH(ns, rr2, c * ii3);        \
    rr2 = nr2; ii2 = ni2; rr3 = nr3; ii3 = ni3; }

    CRX_SLOT1(0)           // i=0: c=q0(b2), t=q1(b1)
    CRX_SLOT0(1)           // i=1: c=q1(b1), t=q2(b0)
    {   // i=2: c=q2(b0: regs 1,3 always ctrl'd), t=q3(b7: lane^32)
        const h2 c = RLH(cvP, 34), s = RLH(svP, 34), ns = NEGH(s);
        const h2 pr1 = BP32(rr1), pi1 = BP32(ii1);
        const h2 pr3 = BP32(rr3), pi3 = BP32(ii3);
        rr1 = FMH(s, pi1, c * rr1); ii1 = FMH(ns, pr1, c * ii1);
        rr3 = FMH(s, pi3, c * rr3); ii3 = FMH(ns, pr3, c * ii3);
    }
    CRX_G(3, 32, BP16)     // i=3: c=b7, t=b6
    CRX_G(4, 16, PX8H)     // i=4: c=b6, t=b5
    CRX_G(5,  8, PX4H)     // i=5: c=b5, t=b4
    CRX_G(6,  4, PX2H)     // i=6: c=b4, t=b3
    CRX_G(7,  2, PX1H)     // i=7: c=b3, t=b2
    CRX_SLOT1(8)           // i=8: same shape as i=0
    CRX_SLOT0(9)           // i=9: same shape as i=1

    // ---- probs (f16) -> f32 epilogue ----
    const h2 pp0 = FMH(rr0, rr0, ii0 * ii0);
    const h2 pp1 = FMH(rr1, rr1, ii1 * ii1);
    const h2 pp2 = FMH(rr2, rr2, ii2 * ii2);
    const h2 pp3 = FMH(rr3, rr3, ii3 * ii3);
    const h2 ap  = (pp0 + pp1) + (pp2 + pp3);
    const float aA = (float)ap.x, aB = (float)ap.y;
    // q3 -> b7 (lane bit5), q7 -> b3 (lane bit1)
    float z3A = (lane & 32) ? -aA : aA, z3B = (lane & 32) ? -aB : aB;
    float z7A = (lane &  2) ? -aA : aA, z7B = (lane &  2) ? -aB : aB;
    z3A += PX1S(z3A); z3B += PX1S(z3B); z7A += PX1S(z7A); z7B += PX1S(z7B);
    z3A += PX2S(z3A); z3B += PX2S(z3B); z7A += PX2S(z7A); z7B += PX2S(z7B);
    z3A += PX4S(z3A); z3B += PX4S(z3B); z7A += PX4S(z7A); z7B += PX4S(z7B);
    z3A += PX8S(z3A); z3B += PX8S(z3B); z7A += PX8S(z7A); z7B += PX8S(z7B);
    z3A += BPFS(a16, z3A); z3B += BPFS(a16, z3B);
    z7A += BPFS(a16, z7A); z7B += BPFS(a16, z7B);
    z3A += BPFS(a32, z3A); z3B += BPFS(a32, z3B);
    z7A += BPFS(a32, z7A); z7B += BPFS(a32, z7B);

    // ---- MLP: lane u (<10) computes hidden unit u for both states ----
    float wa = 0.f, wb = 0.f, bb = 0.f, wc = 0.f;
    if (lane < 10) {
        wa = w1[2 * lane];
        wb = w1[2 * lane + 1];
        bb = b1[lane];
        wc = w2[lane];
    }
    const float zA = fmaf(wa, z3A, fmaf(wb, z7A, bb));
    const float zB = fmaf(wa, z3B, fmaf(wb, z7B, bb));
    const float eA = __expf(2.0f * zA), eB = __expf(2.0f * zB);
    const float hA = 1.0f - 2.0f * __builtin_amdgcn_rcpf(eA + 1.0f);
    const float hB = 1.0f - 2.0f * __builtin_amdgcn_rcpf(eB + 1.0f);
    float accA = wc * hA, accB = wc * hB;    // lanes >=10 contribute 0
    accA += PX1S(accA); accB += PX1S(accB);
    accA += PX2S(accA); accB += PX2S(accB);
    accA += PX4S(accA); accB += PX4S(accB);
    accA += PX8S(accA); accB += PX8S(accB);  // sum over lanes 0..15
    if (lane == 0) {
        const float bias = b2[0];
        out[bA] = __builtin_amdgcn_rcpf(1.0f + __expf(-(accA + bias)));
        out[bB] = __builtin_amdgcn_rcpf(1.0f + __expf(-(accB + bias)));
    }
}

extern "C" void kernel_launch(void* const* d_in, const int* in_sizes, int n_in,
                              void* d_out, int out_size, void* d_ws, size_t ws_size,
                              hipStream_t stream) {
    const float* x         = (const float*)d_in[0];
    const float* crx_theta = (const float*)d_in[1];
    const float* w1        = (const float*)d_in[2];
    const float* b1        = (const float*)d_in[3];
    const float* w2        = (const float*)d_in[4];
    const float* b2        = (const float*)d_in[5];
    float* out = (float*)d_out;

    const int B = in_sizes[0] / 32;  // x is (B, 4, 8)
    vqcnn_wave<<<B / 8, 256, 0, stream>>>(x, crx_theta, w1, b1, w2, b2, out);
}